// Round 12
// baseline (226.334 us; speedup 1.0000x reference)
//
#include <hip/hip_runtime.h>
#include <hip/hip_bf16.h>

typedef __bf16 bf16x8 __attribute__((ext_vector_type(8)));
typedef __bf16 bf16x4 __attribute__((ext_vector_type(4)));
typedef __bf16 bf16x2 __attribute__((ext_vector_type(2)));
typedef float  f32x4  __attribute__((ext_vector_type(4)));

#define MFMA_BF16(a, b, c) __builtin_amdgcn_mfma_f32_16x16x32_bf16((a), (b), (c), 0, 0, 0)

#define GLOAD_LDS16(g, l)                                          \
  __builtin_amdgcn_global_load_lds(                                \
      (const __attribute__((address_space(1))) void*)(g),          \
      (__attribute__((address_space(3))) void*)(l), 16, 0, 0)

static constexpr int kDim = 1024;
static constexpr int kHeads = 16;
static constexpr int kB = 4;
static constexpr int kNKV = 1024;

// ---------------------------------------------------------------------------
// convert5: weights fp32->bf16 + log2(clamped reliability) only. qf/kvf are
// no longer pre-converted — qkv_gemm consumes fp32 A directly (reg-staged
// cvt on its idle VALU pipe). Cuts ~48 MB of pure conversion traffic.
// ---------------------------------------------------------------------------
struct ConvArgs {
  const float* src[4];
  __bf16* dst[4];
  int n4;
  const float* rel;
  float* l2rel;
  int reln4;
};
__global__ __launch_bounds__(256) void convert5(ConvArgs a) {
  const int w = blockIdx.y;
  const int stride = gridDim.x * blockDim.x;
  if (w == 4) {
    for (int i = blockIdx.x * blockDim.x + threadIdx.x; i < a.reln4; i += stride) {
      const float4 v = ((const float4*)a.rel)[i];
      float4 o;
      o.x = __builtin_amdgcn_logf(fmaxf(v.x, 1e-6f));
      o.y = __builtin_amdgcn_logf(fmaxf(v.y, 1e-6f));
      o.z = __builtin_amdgcn_logf(fmaxf(v.z, 1e-6f));
      o.w = __builtin_amdgcn_logf(fmaxf(v.w, 1e-6f));
      ((float4*)a.l2rel)[i] = o;
    }
    return;
  }
  const float4* __restrict__ s = (const float4*)a.src[w];
  __bf16* __restrict__ d = a.dst[w];
  const int n4 = a.n4;
  for (int i = blockIdx.x * blockDim.x + threadIdx.x; i < n4; i += stride) {
    const float4 v = s[i];
    bf16x4 o = {(__bf16)v.x, (__bf16)v.y, (__bf16)v.z, (__bf16)v.w};
    *(bf16x4*)(d + (size_t)i * 4) = o;
  }
}

// ---------------------------------------------------------------------------
// QKV NT-GEMM r17 = r16 (64x128/wave, 128 threads, <41.9us proven) with
// FUSED fp32 A-staging: A is read as fp32 (2 coalesced float4/chunk), cvt'd
// to bf16 in-register, and written to the SAME swizzled LDS layout via
// ds_write_b128 (chunk (row,c) holds global chunk c^(row&7) — frag reads
// unchanged). W stays bf16 via global_load_lds (reused 32x -> pre-convert).
// Removes the qf/kvf convert round-trip (~48 MB); cvt rides the idle VALU.
// ---------------------------------------------------------------------------
struct QKVArgs {
  const float* A[3];       // fp32 now
  const __bf16* W[3];
  const float* bias[3];
  const float* rel;
  __bf16* out[3];
};

__global__ __launch_bounds__(128, 2) void qkv_gemm(QKVArgs args) {
  constexpr int K = kDim;
  constexpr int CT_STRIDE = 136;
  __shared__ __bf16 smem[128 * CT_STRIDE];
  __bf16* const As = smem;
  __bf16* const Bs = smem + 128 * 64;
  __bf16* const Ct = smem;
  const int bid = blockIdx.x;
  const int x = bid & 7, t = bid >> 3;
  const int z = t >> 5, j = t & 31;                 // z slowest: Q, K, V phases
  const int m_blk = (x << 2) + (j >> 3), n_blk = j & 7;
  const int m0 = m_blk << 7, n0 = n_blk << 7;
  const int bb = m_blk >> 3;
  const float* __restrict__ A = args.A[z];
  const __bf16* __restrict__ W = args.W[z];
  const float* __restrict__ bias = args.bias[z];
  const float* __restrict__ rel = args.rel;
  __bf16* __restrict__ out = args.out[z];

  const int tid = threadIdx.x;
  const int wave = tid >> 6, lane = tid & 63;
  const int lr = lane & 15, quad = lane >> 4;
  const int wm = wave << 6;                         // wave owns 64 m-rows

  f32x4 acc[4][8] = {};

  for (int k0 = 0; k0 < K; k0 += 64) {
    __syncthreads();
#pragma unroll
    for (int i = 0; i < 8; ++i) {               // A: fp32 reg-staged + cvt
      const int sc = tid + (i << 7);
      const int row = sc >> 3, cp = sc & 7;
      const float* src = A + (size_t)(m0 + row) * K + k0 + (cp << 3);
      const f32x4 f0 = *(const f32x4*)src;
      const f32x4 f1 = *(const f32x4*)(src + 4);
      bf16x8 v;
      v[0] = (__bf16)f0[0]; v[1] = (__bf16)f0[1];
      v[2] = (__bf16)f0[2]; v[3] = (__bf16)f0[3];
      v[4] = (__bf16)f1[0]; v[5] = (__bf16)f1[1];
      v[6] = (__bf16)f1[2]; v[7] = (__bf16)f1[3];
      *(bf16x8*)&As[(((row << 3) + (cp ^ (row & 7)))) << 3] = v;
    }
#pragma unroll
    for (int i = 0; i < 8; ++i) {               // B: bf16 gload_lds (as before)
      const int sc = tid + (i << 7);
      const int row = sc >> 3, cp = sc & 7;
      const int gcol = (cp ^ (row & 7)) << 3;
      GLOAD_LDS16(W + (size_t)(n0 + row) * K + k0 + gcol, Bs + sc * 8);
    }
    __syncthreads();
#pragma unroll
    for (int kk = 0; kk < 2; ++kk) {
      bf16x8 afr[4], bfr[8];
#pragma unroll
      for (int mi = 0; mi < 4; ++mi) {
        const int row = wm + mi * 16 + lr;
        afr[mi] = *(const bf16x8*)&As[(row << 6) +
                                      ((((kk << 2) + quad) ^ (row & 7)) << 3)];
      }
#pragma unroll
      for (int ni = 0; ni < 8; ++ni) {
        const int row = ni * 16 + lr;
        bfr[ni] = *(const bf16x8*)&Bs[(row << 6) +
                                      ((((kk << 2) + quad) ^ (row & 7)) << 3)];
      }
#pragma unroll
      for (int mi = 0; mi < 4; ++mi)
#pragma unroll
        for (int ni = 0; ni < 8; ++ni)
          acc[mi][ni] = MFMA_BF16(afr[mi], bfr[ni], acc[mi][ni]);
    }
  }

  // All waves done reading As/Bs before Ct (same storage) is written.
  __syncthreads();

  // Epilogue: D layout row=(lane>>4)*4+r, col=lane&15 (verified).
#pragma unroll
  for (int mi = 0; mi < 4; ++mi)
#pragma unroll
    for (int ni = 0; ni < 8; ++ni) {
      const int col_l = ni * 16 + lr;
      const float bc = bias[n0 + col_l];
      const f32x4 v = acc[mi][ni];
      const int row0 = wm + mi * 16 + (quad << 2);
      if (z == 2) {
        const f32x4 r4 = *(const f32x4*)(rel + (bb << 10) + ((m0 + row0) & 1023));
        bf16x4 pk;
#pragma unroll
        for (int r = 0; r < 4; ++r) pk[r] = (__bf16)((v[r] + bc) * r4[r]);
        *(bf16x4*)&Ct[col_l * CT_STRIDE + row0] = pk;
      } else if (z == 1) {
        const f32x4 r4 = *(const f32x4*)(rel + (bb << 10) + ((m0 + row0) & 1023));
#pragma unroll
        for (int r = 0; r < 4; ++r)
          Ct[(row0 + r) * CT_STRIDE + col_l] = (__bf16)((v[r] + bc) * r4[r]);
      } else {
#pragma unroll
        for (int r = 0; r < 4; ++r)
          Ct[(row0 + r) * CT_STRIDE + col_l] = (__bf16)(v[r] + bc);
      }
    }
  __syncthreads();

  const int hh0 = n0 >> 6;
  if (z == 2) {
#pragma unroll
    for (int jj = 0; jj < 16; ++jj) {
      const int idx = (jj << 7) + tid;
      const int c = idx >> 4, r8 = (idx & 15) << 3;
      const bf16x8 vv = *(const bf16x8*)&Ct[c * CT_STRIDE + r8];
      const int col = n0 + c;
      const int hh = col >> 6, dd = col & 63;
      *(bf16x8*)(out + ((size_t)(bb * kHeads + hh) * 64 + dd) * 1024 +
                 (m0 & 1023) + r8) = vv;
    }
  } else {
#pragma unroll
    for (int jj = 0; jj < 16; ++jj) {
      const int idx = (jj << 7) + tid;
      const int r = idx >> 4, c8 = (idx & 15) << 3;
      const bf16x8 vv = *(const bf16x8*)&Ct[r * CT_STRIDE + c8];
      const int hh = hh0 + (c8 >> 6), dd = c8 & 63;
      *(bf16x8*)(out + ((size_t)(bb * kHeads + hh) << 16) +
                 (size_t)((m0 & 1023) + r) * 64 + dd) = vv;
    }
  }
}

// ---------------------------------------------------------------------------
// O-projection r13 (round-8 winner, unchanged: 128x64 tile, 512 blocks =
// 2 blocks/CU, dbuf + counted vmcnt(6)).
// ---------------------------------------------------------------------------
__global__ __launch_bounds__(256) void o_gemm(const __bf16* __restrict__ A,
                                              const __bf16* __restrict__ W,
                                              const float* __restrict__ bias,
                                              float* __restrict__ out) {
  constexpr int K = kDim;
  __shared__ __bf16 As[2][128 * 64];
  __shared__ __bf16 Bs[2][64 * 64];
  const int bid = blockIdx.x;
  const int x = bid & 7, t = bid >> 3;
  const int m_blk = (x << 2) + (t & 3), n_blk = t >> 2;
  const int m0 = m_blk << 7, n0 = n_blk << 6;
  const int tid = threadIdx.x;
  const int wave = tid >> 6, lane = tid & 63;
  const int lr = lane & 15, quad = lane >> 4;
  const int wm = wave << 5;

  const __bf16* aP[4];
  int soA[4];
#pragma unroll
  for (int i = 0; i < 4; ++i) {
    const int sc = tid + (i << 8);
    const int row = sc >> 3, cp = sc & 7;
    const int gcol = (cp ^ (row & 7)) << 3;
    aP[i] = A + (size_t)(m0 + row) * K + gcol;
    soA[i] = sc * 8;
  }
  const __bf16* bP[2];
  int soB[2];
#pragma unroll
  for (int i = 0; i < 2; ++i) {
    const int sc = tid + (i << 8);
    const int row = sc >> 3, cp = sc & 7;
    const int gcol = (cp ^ (row & 7)) << 3;
    bP[i] = W + (size_t)(n0 + row) * K + gcol;
    soB[i] = sc * 8;
  }

#pragma unroll
  for (int i = 0; i < 4; ++i) GLOAD_LDS16(aP[i], &As[0][soA[i]]);
#pragma unroll
  for (int i = 0; i < 2; ++i) GLOAD_LDS16(bP[i], &Bs[0][soB[i]]);

  f32x4 acc[2][4] = {};
  for (int tile = 0; tile < 16; ++tile) {
    const int cur = tile & 1;
    if (tile < 15) {
      const int k0 = (tile + 1) << 6;
      const int nxt = cur ^ 1;
#pragma unroll
      for (int i = 0; i < 4; ++i) GLOAD_LDS16(aP[i] + k0, &As[nxt][soA[i]]);
#pragma unroll
      for (int i = 0; i < 2; ++i) GLOAD_LDS16(bP[i] + k0, &Bs[nxt][soB[i]]);
      asm volatile("s_waitcnt vmcnt(6)" ::: "memory");
    } else {
      asm volatile("s_waitcnt vmcnt(0)" ::: "memory");
    }
    __builtin_amdgcn_s_barrier();
    __builtin_amdgcn_sched_barrier(0);

    const __bf16* Asc = As[cur];
    const __bf16* Bsc = Bs[cur];
#pragma unroll
    for (int kk = 0; kk < 2; ++kk) {
      bf16x8 afr[2], bfr[4];
#pragma unroll
      for (int mi = 0; mi < 2; ++mi) {
        const int row = wm + mi * 16 + lr;
        afr[mi] = *(const bf16x8*)&Asc[(row << 6) +
                                       ((((kk << 2) + quad) ^ (row & 7)) << 3)];
      }
#pragma unroll
      for (int ni = 0; ni < 4; ++ni) {
        const int row = ni * 16 + lr;
        bfr[ni] = *(const bf16x8*)&Bsc[(row << 6) +
                                       ((((kk << 2) + quad) ^ (row & 7)) << 3)];
      }
#pragma unroll
      for (int mi = 0; mi < 2; ++mi)
#pragma unroll
        for (int ni = 0; ni < 4; ++ni)
          acc[mi][ni] = MFMA_BF16(afr[mi], bfr[ni], acc[mi][ni]);
    }
    asm volatile("" ::: "memory");
    __builtin_amdgcn_sched_barrier(0);
    __builtin_amdgcn_s_barrier();
  }

#pragma unroll
  for (int mi = 0; mi < 2; ++mi)
#pragma unroll
    for (int ni = 0; ni < 4; ++ni) {
      const int col = n0 + ni * 16 + lr;
      const float bc = bias[col];
      const f32x4 v = acc[mi][ni];
#pragma unroll
      for (int r = 0; r < 4; ++r) {
        const int row = m0 + wm + mi * 16 + (quad << 2) + r;
        out[(size_t)row * kDim + col] = v[r] + bc;
      }
    }
}

// ---------------------------------------------------------------------------
// Fused attention r14 (round-8 winner, unchanged): unified, dbuf + counted
// vmcnt(4), LDS log2-rel, ds_permute P-redistribution, ones-column MFMA
// denominator.
// ---------------------------------------------------------------------------
__global__ __launch_bounds__(256, 4) void attn_fused(const __bf16* __restrict__ Qb,
                                                     const __bf16* __restrict__ Kb,
                                                     const __bf16* __restrict__ Vb,
                                                     const float* __restrict__ l2rel,
                                                     __bf16* __restrict__ AO) {
  __shared__ __bf16 Klds[2][64 * 64];
  __shared__ __bf16 Vlds[2][64 * 64];
  __shared__ float Rlds[1024];
  const int tid = threadIdx.x;
  const int wave = tid >> 6, lane = tid & 63;
  const int lr = lane & 15, quad = lane >> 4;
  const int x = blockIdx.x & 7, g = blockIdx.x >> 3;
  const int hg = x + ((g & 7) << 3);
  const int b = hg >> 4, h = hg & 15, q0 = (g >> 3) << 6;
  const __bf16* Qh = Qb + ((size_t)hg << 16);
  const __bf16* Kh = Kb + ((size_t)hg << 16);
  const __bf16* Vh = Vb + ((size_t)hg << 16);
  const float* rb = l2rel + (b << 10);

  ((f32x4*)Rlds)[tid] = ((const f32x4*)rb)[tid];

  const __bf16* qrow = Qh + (q0 + (wave << 4) + lr) * 64 + (quad << 3);
  const bf16x8 qf0 = *(const bf16x8*)qrow;
  const bf16x8 qf1 = *(const bf16x8*)(qrow + 32);

  const int r0 = tid >> 3, c0 = tid & 7;
  const int gc0 = (c0 ^ (r0 & 7)) << 3;
  const int r1 = (tid + 256) >> 3;
  const int gc1 = (c0 ^ (r1 & 7)) << 3;
  const __bf16* kg0 = Kh + (size_t)r0 * 64 + gc0;
  const __bf16* kg1 = Kh + (size_t)r1 * 64 + gc1;
  const __bf16* vg0 = Vh + (size_t)r0 * kNKV + gc0;
  const __bf16* vg1 = Vh + (size_t)r1 * kNKV + gc1;

  asm volatile("s_waitcnt lgkmcnt(0)" ::: "memory");

  GLOAD_LDS16(kg0, &Klds[0][tid * 8]);
  GLOAD_LDS16(kg1, &Klds[0][(tid + 256) * 8]);
  GLOAD_LDS16(vg0, &Vlds[0][tid * 8]);
  GLOAD_LDS16(vg1, &Vlds[0][(tid + 256) * 8]);

  f32x4 accO[4] = {{0.f, 0.f, 0.f, 0.f}, {0.f, 0.f, 0.f, 0.f},
                   {0.f, 0.f, 0.f, 0.f}, {0.f, 0.f, 0.f, 0.f}};
  f32x4 accL = {0.f, 0.f, 0.f, 0.f};
  const bf16x8 onesf = {(__bf16)1.f, (__bf16)1.f, (__bf16)1.f, (__bf16)1.f,
                        (__bf16)1.f, (__bf16)1.f, (__bf16)1.f, (__bf16)1.f};
  const int xk = lr & 7;
  constexpr float kC = 0.125f * 1.44269504088896341f;  // scale * log2(e)

  const int addrA = ((((quad & 1) << 1) + (quad >> 1)) << 6) + (lr << 2);
  const int addrB = addrA ^ 128;
  const bool qodd = (quad & 1) != 0;
  const bool hiq = quad >= 2;

  for (int it = 0; it < 16; ++it) {
    const int cur = it & 1;
    if (it < 15) {
      const int nxt = cur ^ 1;
      const size_t kofs = (size_t)(it + 1) << 12;
      const size_t vofs = (size_t)(it + 1) << 6;
      GLOAD_LDS16(kg0 + kofs, &Klds[nxt][tid * 8]);
      GLOAD_LDS16(kg1 + kofs, &Klds[nxt][(tid + 256) * 8]);
      GLOAD_LDS16(vg0 + vofs, &Vlds[nxt][tid * 8]);
      GLOAD_LDS16(vg1 + vofs, &Vlds[nxt][(tid + 256) * 8]);
      asm volatile("s_waitcnt vmcnt(4)" ::: "memory");
    } else {
      asm volatile("s_waitcnt vmcnt(0)" ::: "memory");
    }
    __builtin_amdgcn_s_barrier();
    __builtin_amdgcn_sched_barrier(0);

    const int kv0 = it << 6;
#pragma unroll
    for (int s = 0; s < 2; ++s) {
      int tt[2][2];
#pragma unroll
      for (int half = 0; half < 2; ++half) {
        const int kvt = (s << 1) + half;
        const int kr = ((kvt << 4) + lr) << 6;
        const bf16x8 ka0 = *(const bf16x8*)&Klds[cur][kr + ((quad ^ xk) << 3)];
        const bf16x8 ka1 = *(const bf16x8*)&Klds[cur][kr + (((4 + quad) ^ xk) << 3)];
        f32x4 d = {0.f, 0.f, 0.f, 0.f};
        __builtin_amdgcn_s_setprio(1);
        d = MFMA_BF16(ka0, qf0, d);
        d = MFMA_BF16(ka1, qf1, d);
        __builtin_amdgcn_s_setprio(0);
        const f32x4 lg = *(const f32x4*)&Rlds[kv0 + (kvt << 4) + (quad << 2)];
        const float p0 = __builtin_amdgcn_exp2f(fmaf(d[0], kC, lg[0]));
        const float p1 = __builtin_amdgcn_exp2f(fmaf(d[1], kC, lg[1]));
        const float p2 = __builtin_amdgcn_exp2f(fmaf(d[2], kC, lg[2]));
        const float p3 = __builtin_amdgcn_exp2f(fmaf(d[3], kC, lg[3]));
        bf16x2 lo2 = {(__bf16)p0, (__bf16)p1};
        bf16x2 hi2 = {(__bf16)p2, (__bf16)p3};
        tt[half][0] = __builtin_bit_cast(int, lo2);
        tt[half][1] = __builtin_bit_cast(int, hi2);
      }
      const int vA0 = qodd ? tt[1][0] : tt[0][0];
      const int vA1 = qodd ? tt[1][1] : tt[0][1];
      const int vB0 = qodd ? tt[0][0] : tt[1][0];
      const int vB1 = qodd ? tt[0][1] : tt[1][1];
      const int ra0 = __builtin_amdgcn_ds_permute(addrA, vA0);
      const int ra1 = __builtin_amdgcn_ds_permute(addrA, vA1);
      const int rb0 = __builtin_amdgcn_ds_permute(addrB, vB0);
      const int rb1 = __builtin_amdgcn_ds_permute(addrB, vB1);
      int4 ai;
      ai.x = hiq ? rb0 : ra0;
      ai.y = hiq ? rb1 : ra1;
      ai.z = hiq ? ra0 : rb0;
      ai.w = hiq ? ra1 : rb1;
      const bf16x8 pa = __builtin_bit_cast(bf16x8, ai);
      __builtin_amdgcn_s_setprio(1);
      accL = MFMA_BF16(pa, onesf, accL);
#pragma unroll
      for (int dt = 0; dt < 4; ++dt) {
        const bf16x8 vb = *(const bf16x8*)&Vlds[cur][(((dt << 4) + lr) << 6) +
                                                     ((((s << 2) + quad) ^ xk) << 3)];
        accO[dt] = MFMA_BF16(pa, vb, accO[dt]);
      }
      __builtin_amdgcn_s_setprio(0);
    }
    asm volatile("" ::: "memory");
    __builtin_amdgcn_sched_barrier(0);
    __builtin_amdgcn_s_barrier();
  }

  float linv[4];
#pragma unroll
  for (int r = 0; r < 4; ++r) linv[r] = 1.f / accL[r];

#pragma unroll
  for (int dt = 0; dt < 4; ++dt) {
    const int dcol = (h << 6) + (dt << 4) + lr;
#pragma unroll
    for (int r = 0; r < 4; ++r) {
      const int qg = q0 + (wave << 4) + (quad << 2) + r;
      AO[((size_t)(b << 10) + qg) * kDim + dcol] = (__bf16)(accO[dt][r] * linv[r]);
    }
  }
}

extern "C" void kernel_launch(void* const* d_in, const int* in_sizes, int n_in,
                              void* d_out, int out_size, void* d_ws, size_t ws_size,
                              hipStream_t stream) {
  (void)in_sizes; (void)n_in; (void)out_size; (void)ws_size;
  const float* qf  = (const float*)d_in[0];
  const float* kvf = (const float*)d_in[1];
  const float* rel = (const float*)d_in[2];
  const float* Wq  = (const float*)d_in[3];
  const float* bq  = (const float*)d_in[4];
  const float* Wk  = (const float*)d_in[5];
  const float* bk  = (const float*)d_in[6];
  const float* Wv  = (const float*)d_in[7];
  const float* bv  = (const float*)d_in[8];
  const float* Wo  = (const float*)d_in[9];
  const float* bo  = (const float*)d_in[10];

  const size_t big = (size_t)kB * 1024 * kDim;  // 4M elements
  __bf16* p = (__bf16*)d_ws;
  __bf16* cWq  = p; p += kDim * kDim;
  __bf16* cWk  = p; p += kDim * kDim;
  __bf16* cWv  = p; p += kDim * kDim;
  __bf16* cWo  = p; p += kDim * kDim;
  __bf16* q_buf  = p; p += big;
  __bf16* k_buf  = p; p += big;
  __bf16* vT_buf = p; p += big;
  __bf16* ao_buf = p; p += big;
  float* l2rel = (float*)p;  // 4096 floats (16 KB)

  ConvArgs cv;
  const float* srcs[4] = {Wq, Wk, Wv, Wo};
  __bf16* dsts[4] = {cWq, cWk, cWv, cWo};
  for (int i = 0; i < 4; ++i) { cv.src[i] = srcs[i]; cv.dst[i] = dsts[i]; }
  cv.n4 = kDim * kDim / 4;
  cv.rel = rel;
  cv.l2rel = l2rel;
  cv.reln4 = (kB * kNKV) / 4;
  convert5<<<dim3(256, 5), 256, 0, stream>>>(cv);

  QKVArgs qa;
  qa.A[0] = qf;   qa.A[1] = kvf;  qa.A[2] = kvf;
  qa.W[0] = cWq;  qa.W[1] = cWk;  qa.W[2] = cWv;
  qa.bias[0] = bq; qa.bias[1] = bk; qa.bias[2] = bv;
  qa.rel = rel;
  qa.out[0] = q_buf; qa.out[1] = k_buf; qa.out[2] = vT_buf;
  qkv_gemm<<<768, 128, 0, stream>>>(qa);

  attn_fused<<<kB * kHeads * (1024 / 64), 256, 0, stream>>>(q_buf, k_buf, vT_buf, l2rel, ao_buf);

  o_gemm<<<512, 256, 0, stream>>>(ao_buf, cWo, bo, (float*)d_out);
}

// Round 13
// 187.848 us; speedup vs baseline: 1.2049x; 1.2049x over previous
//
#include <hip/hip_runtime.h>
#include <hip/hip_bf16.h>

typedef __bf16 bf16x8 __attribute__((ext_vector_type(8)));
typedef __bf16 bf16x4 __attribute__((ext_vector_type(4)));
typedef __bf16 bf16x2 __attribute__((ext_vector_type(2)));
typedef float  f32x4  __attribute__((ext_vector_type(4)));

#define MFMA_BF16(a, b, c) __builtin_amdgcn_mfma_f32_16x16x32_bf16((a), (b), (c), 0, 0, 0)

#define GLOAD_LDS16(g, l)                                          \
  __builtin_amdgcn_global_load_lds(                                \
      (const __attribute__((address_space(1))) void*)(g),          \
      (__attribute__((address_space(3))) void*)(l), 16, 0, 0)

static constexpr int kDim = 1024;
static constexpr int kHeads = 16;
static constexpr int kB = 4;
static constexpr int kNKV = 1024;

// ---------------------------------------------------------------------------
// fp32 -> bf16 canonicalization + log2(clamped reliability) precompute.
// (Round-12 lesson: do NOT fuse qf/kvf conversion into qkv via reg-staging —
// replacing async global_load_lds with a synchronous load+cvt+ds_write chain
// cost 2.4x on a 2-wave kernel. Pre-convert stays.)
// ---------------------------------------------------------------------------
struct ConvArgs {
  const float* src[6];
  __bf16* dst[6];
  int n4[6];
  const float* rel;
  float* l2rel;
  int reln4;
};
__global__ __launch_bounds__(256) void convert7(ConvArgs a) {
  const int w = blockIdx.y;
  const int stride = gridDim.x * blockDim.x;
  if (w == 6) {
    for (int i = blockIdx.x * blockDim.x + threadIdx.x; i < a.reln4; i += stride) {
      const float4 v = ((const float4*)a.rel)[i];
      float4 o;
      o.x = __builtin_amdgcn_logf(fmaxf(v.x, 1e-6f));
      o.y = __builtin_amdgcn_logf(fmaxf(v.y, 1e-6f));
      o.z = __builtin_amdgcn_logf(fmaxf(v.z, 1e-6f));
      o.w = __builtin_amdgcn_logf(fmaxf(v.w, 1e-6f));
      ((float4*)a.l2rel)[i] = o;
    }
    return;
  }
  const float4* __restrict__ s = (const float4*)a.src[w];
  __bf16* __restrict__ d = a.dst[w];
  const int n4 = a.n4[w];
  for (int i = blockIdx.x * blockDim.x + threadIdx.x; i < n4; i += stride) {
    const float4 v = s[i];
    bf16x4 o = {(__bf16)v.x, (__bf16)v.y, (__bf16)v.z, (__bf16)v.w};
    *(bf16x4*)(d + (size_t)i * 4) = o;
  }
}

// ---------------------------------------------------------------------------
// QKV NT-GEMM r16 (round-11 winner, restored): 128x128 tile, 768 blocks,
// 34816 B LDS (Ct aliased), 128-thread 2-wave blocks, each wave owns 64x128
// (acc[4][8]) -> 0.375 LDS reads/MFMA (25% less read traffic than 4-wave
// 64x64 on the proven LDS-BW-bound pipe). A/W both bf16 via global_load_lds.
// ---------------------------------------------------------------------------
struct QKVArgs {
  const __bf16* A[3];
  const __bf16* W[3];
  const float* bias[3];
  const float* rel;
  __bf16* out[3];
};

__global__ __launch_bounds__(128, 2) void qkv_gemm(QKVArgs args) {
  constexpr int K = kDim;
  constexpr int CT_STRIDE = 136;
  __shared__ __bf16 smem[128 * CT_STRIDE];
  __bf16* const As = smem;
  __bf16* const Bs = smem + 128 * 64;
  __bf16* const Ct = smem;
  const int bid = blockIdx.x;
  const int x = bid & 7, t = bid >> 3;
  const int z = t >> 5, j = t & 31;                 // z slowest: Q, K, V phases
  const int m_blk = (x << 2) + (j >> 3), n_blk = j & 7;
  const int m0 = m_blk << 7, n0 = n_blk << 7;
  const int bb = m_blk >> 3;
  const __bf16* __restrict__ A = args.A[z];
  const __bf16* __restrict__ W = args.W[z];
  const float* __restrict__ bias = args.bias[z];
  const float* __restrict__ rel = args.rel;
  __bf16* __restrict__ out = args.out[z];

  const int tid = threadIdx.x;
  const int wave = tid >> 6, lane = tid & 63;
  const int lr = lane & 15, quad = lane >> 4;
  const int wm = wave << 6;                         // wave owns 64 m-rows

  f32x4 acc[4][8] = {};

  for (int k0 = 0; k0 < K; k0 += 64) {
    __syncthreads();
#pragma unroll
    for (int i = 0; i < 8; ++i) {               // A: 1024 16B chunks
      const int sc = tid + (i << 7);
      const int row = sc >> 3, cp = sc & 7;
      const int gcol = (cp ^ (row & 7)) << 3;
      GLOAD_LDS16(A + (size_t)(m0 + row) * K + k0 + gcol, As + sc * 8);
    }
#pragma unroll
    for (int i = 0; i < 8; ++i) {               // B: 1024 16B chunks
      const int sc = tid + (i << 7);
      const int row = sc >> 3, cp = sc & 7;
      const int gcol = (cp ^ (row & 7)) << 3;
      GLOAD_LDS16(W + (size_t)(n0 + row) * K + k0 + gcol, Bs + sc * 8);
    }
    __syncthreads();
#pragma unroll
    for (int kk = 0; kk < 2; ++kk) {
      bf16x8 afr[4], bfr[8];
#pragma unroll
      for (int mi = 0; mi < 4; ++mi) {
        const int row = wm + mi * 16 + lr;
        afr[mi] = *(const bf16x8*)&As[(row << 6) +
                                      ((((kk << 2) + quad) ^ (row & 7)) << 3)];
      }
#pragma unroll
      for (int ni = 0; ni < 8; ++ni) {
        const int row = ni * 16 + lr;
        bfr[ni] = *(const bf16x8*)&Bs[(row << 6) +
                                      ((((kk << 2) + quad) ^ (row & 7)) << 3)];
      }
#pragma unroll
      for (int mi = 0; mi < 4; ++mi)
#pragma unroll
        for (int ni = 0; ni < 8; ++ni)
          acc[mi][ni] = MFMA_BF16(afr[mi], bfr[ni], acc[mi][ni]);
    }
  }

  // All waves done reading As/Bs before Ct (same storage) is written.
  __syncthreads();

  // Epilogue: D layout row=(lane>>4)*4+r, col=lane&15 (verified).
#pragma unroll
  for (int mi = 0; mi < 4; ++mi)
#pragma unroll
    for (int ni = 0; ni < 8; ++ni) {
      const int col_l = ni * 16 + lr;
      const float bc = bias[n0 + col_l];
      const f32x4 v = acc[mi][ni];
      const int row0 = wm + mi * 16 + (quad << 2);
      if (z == 2) {
        const f32x4 r4 = *(const f32x4*)(rel + (bb << 10) + ((m0 + row0) & 1023));
        bf16x4 pk;
#pragma unroll
        for (int r = 0; r < 4; ++r) pk[r] = (__bf16)((v[r] + bc) * r4[r]);
        *(bf16x4*)&Ct[col_l * CT_STRIDE + row0] = pk;
      } else if (z == 1) {
        const f32x4 r4 = *(const f32x4*)(rel + (bb << 10) + ((m0 + row0) & 1023));
#pragma unroll
        for (int r = 0; r < 4; ++r)
          Ct[(row0 + r) * CT_STRIDE + col_l] = (__bf16)((v[r] + bc) * r4[r]);
      } else {
#pragma unroll
        for (int r = 0; r < 4; ++r)
          Ct[(row0 + r) * CT_STRIDE + col_l] = (__bf16)(v[r] + bc);
      }
    }
  __syncthreads();

  const int hh0 = n0 >> 6;
  if (z == 2) {
#pragma unroll
    for (int jj = 0; jj < 16; ++jj) {
      const int idx = (jj << 7) + tid;
      const int c = idx >> 4, r8 = (idx & 15) << 3;
      const bf16x8 vv = *(const bf16x8*)&Ct[c * CT_STRIDE + r8];
      const int col = n0 + c;
      const int hh = col >> 6, dd = col & 63;
      *(bf16x8*)(out + ((size_t)(bb * kHeads + hh) * 64 + dd) * 1024 +
                 (m0 & 1023) + r8) = vv;
    }
  } else {
#pragma unroll
    for (int jj = 0; jj < 16; ++jj) {
      const int idx = (jj << 7) + tid;
      const int r = idx >> 4, c8 = (idx & 15) << 3;
      const bf16x8 vv = *(const bf16x8*)&Ct[r * CT_STRIDE + c8];
      const int hh = hh0 + (c8 >> 6), dd = c8 & 63;
      *(bf16x8*)(out + ((size_t)(bb * kHeads + hh) << 16) +
                 (size_t)((m0 & 1023) + r) * 64 + dd) = vv;
    }
  }
}

// ---------------------------------------------------------------------------
// O-projection r13 (round-8 winner, unchanged: 128x64 tile, 512 blocks =
// 2 blocks/CU, dbuf + counted vmcnt(6)).
// ---------------------------------------------------------------------------
__global__ __launch_bounds__(256) void o_gemm(const __bf16* __restrict__ A,
                                              const __bf16* __restrict__ W,
                                              const float* __restrict__ bias,
                                              float* __restrict__ out) {
  constexpr int K = kDim;
  __shared__ __bf16 As[2][128 * 64];
  __shared__ __bf16 Bs[2][64 * 64];
  const int bid = blockIdx.x;
  const int x = bid & 7, t = bid >> 3;
  const int m_blk = (x << 2) + (t & 3), n_blk = t >> 2;
  const int m0 = m_blk << 7, n0 = n_blk << 6;
  const int tid = threadIdx.x;
  const int wave = tid >> 6, lane = tid & 63;
  const int lr = lane & 15, quad = lane >> 4;
  const int wm = wave << 5;

  const __bf16* aP[4];
  int soA[4];
#pragma unroll
  for (int i = 0; i < 4; ++i) {
    const int sc = tid + (i << 8);
    const int row = sc >> 3, cp = sc & 7;
    const int gcol = (cp ^ (row & 7)) << 3;
    aP[i] = A + (size_t)(m0 + row) * K + gcol;
    soA[i] = sc * 8;
  }
  const __bf16* bP[2];
  int soB[2];
#pragma unroll
  for (int i = 0; i < 2; ++i) {
    const int sc = tid + (i << 8);
    const int row = sc >> 3, cp = sc & 7;
    const int gcol = (cp ^ (row & 7)) << 3;
    bP[i] = W + (size_t)(n0 + row) * K + gcol;
    soB[i] = sc * 8;
  }

#pragma unroll
  for (int i = 0; i < 4; ++i) GLOAD_LDS16(aP[i], &As[0][soA[i]]);
#pragma unroll
  for (int i = 0; i < 2; ++i) GLOAD_LDS16(bP[i], &Bs[0][soB[i]]);

  f32x4 acc[2][4] = {};
  for (int tile = 0; tile < 16; ++tile) {
    const int cur = tile & 1;
    if (tile < 15) {
      const int k0 = (tile + 1) << 6;
      const int nxt = cur ^ 1;
#pragma unroll
      for (int i = 0; i < 4; ++i) GLOAD_LDS16(aP[i] + k0, &As[nxt][soA[i]]);
#pragma unroll
      for (int i = 0; i < 2; ++i) GLOAD_LDS16(bP[i] + k0, &Bs[nxt][soB[i]]);
      asm volatile("s_waitcnt vmcnt(6)" ::: "memory");
    } else {
      asm volatile("s_waitcnt vmcnt(0)" ::: "memory");
    }
    __builtin_amdgcn_s_barrier();
    __builtin_amdgcn_sched_barrier(0);

    const __bf16* Asc = As[cur];
    const __bf16* Bsc = Bs[cur];
#pragma unroll
    for (int kk = 0; kk < 2; ++kk) {
      bf16x8 afr[2], bfr[4];
#pragma unroll
      for (int mi = 0; mi < 2; ++mi) {
        const int row = wm + mi * 16 + lr;
        afr[mi] = *(const bf16x8*)&Asc[(row << 6) +
                                       ((((kk << 2) + quad) ^ (row & 7)) << 3)];
      }
#pragma unroll
      for (int ni = 0; ni < 4; ++ni) {
        const int row = ni * 16 + lr;
        bfr[ni] = *(const bf16x8*)&Bsc[(row << 6) +
                                       ((((kk << 2) + quad) ^ (row & 7)) << 3)];
      }
#pragma unroll
      for (int mi = 0; mi < 2; ++mi)
#pragma unroll
        for (int ni = 0; ni < 4; ++ni)
          acc[mi][ni] = MFMA_BF16(afr[mi], bfr[ni], acc[mi][ni]);
    }
    asm volatile("" ::: "memory");
    __builtin_amdgcn_sched_barrier(0);
    __builtin_amdgcn_s_barrier();
  }

#pragma unroll
  for (int mi = 0; mi < 2; ++mi)
#pragma unroll
    for (int ni = 0; ni < 4; ++ni) {
      const int col = n0 + ni * 16 + lr;
      const float bc = bias[col];
      const f32x4 v = acc[mi][ni];
#pragma unroll
      for (int r = 0; r < 4; ++r) {
        const int row = m0 + wm + mi * 16 + (quad << 2) + r;
        out[(size_t)row * kDim + col] = v[r] + bc;
      }
    }
}

// ---------------------------------------------------------------------------
// Fused attention r14 (round-8 winner, unchanged): unified, dbuf + counted
// vmcnt(4), LDS log2-rel, ds_permute P-redistribution, ones-column MFMA
// denominator.
// ---------------------------------------------------------------------------
__global__ __launch_bounds__(256, 4) void attn_fused(const __bf16* __restrict__ Qb,
                                                     const __bf16* __restrict__ Kb,
                                                     const __bf16* __restrict__ Vb,
                                                     const float* __restrict__ l2rel,
                                                     __bf16* __restrict__ AO) {
  __shared__ __bf16 Klds[2][64 * 64];
  __shared__ __bf16 Vlds[2][64 * 64];
  __shared__ float Rlds[1024];
  const int tid = threadIdx.x;
  const int wave = tid >> 6, lane = tid & 63;
  const int lr = lane & 15, quad = lane >> 4;
  const int x = blockIdx.x & 7, g = blockIdx.x >> 3;
  const int hg = x + ((g & 7) << 3);
  const int b = hg >> 4, h = hg & 15, q0 = (g >> 3) << 6;
  const __bf16* Qh = Qb + ((size_t)hg << 16);
  const __bf16* Kh = Kb + ((size_t)hg << 16);
  const __bf16* Vh = Vb + ((size_t)hg << 16);
  const float* rb = l2rel + (b << 10);

  ((f32x4*)Rlds)[tid] = ((const f32x4*)rb)[tid];

  const __bf16* qrow = Qh + (q0 + (wave << 4) + lr) * 64 + (quad << 3);
  const bf16x8 qf0 = *(const bf16x8*)qrow;
  const bf16x8 qf1 = *(const bf16x8*)(qrow + 32);

  const int r0 = tid >> 3, c0 = tid & 7;
  const int gc0 = (c0 ^ (r0 & 7)) << 3;
  const int r1 = (tid + 256) >> 3;
  const int gc1 = (c0 ^ (r1 & 7)) << 3;
  const __bf16* kg0 = Kh + (size_t)r0 * 64 + gc0;
  const __bf16* kg1 = Kh + (size_t)r1 * 64 + gc1;
  const __bf16* vg0 = Vh + (size_t)r0 * kNKV + gc0;
  const __bf16* vg1 = Vh + (size_t)r1 * kNKV + gc1;

  asm volatile("s_waitcnt lgkmcnt(0)" ::: "memory");

  GLOAD_LDS16(kg0, &Klds[0][tid * 8]);
  GLOAD_LDS16(kg1, &Klds[0][(tid + 256) * 8]);
  GLOAD_LDS16(vg0, &Vlds[0][tid * 8]);
  GLOAD_LDS16(vg1, &Vlds[0][(tid + 256) * 8]);

  f32x4 accO[4] = {{0.f, 0.f, 0.f, 0.f}, {0.f, 0.f, 0.f, 0.f},
                   {0.f, 0.f, 0.f, 0.f}, {0.f, 0.f, 0.f, 0.f}};
  f32x4 accL = {0.f, 0.f, 0.f, 0.f};
  const bf16x8 onesf = {(__bf16)1.f, (__bf16)1.f, (__bf16)1.f, (__bf16)1.f,
                        (__bf16)1.f, (__bf16)1.f, (__bf16)1.f, (__bf16)1.f};
  const int xk = lr & 7;
  constexpr float kC = 0.125f * 1.44269504088896341f;  // scale * log2(e)

  const int addrA = ((((quad & 1) << 1) + (quad >> 1)) << 6) + (lr << 2);
  const int addrB = addrA ^ 128;
  const bool qodd = (quad & 1) != 0;
  const bool hiq = quad >= 2;

  for (int it = 0; it < 16; ++it) {
    const int cur = it & 1;
    if (it < 15) {
      const int nxt = cur ^ 1;
      const size_t kofs = (size_t)(it + 1) << 12;
      const size_t vofs = (size_t)(it + 1) << 6;
      GLOAD_LDS16(kg0 + kofs, &Klds[nxt][tid * 8]);
      GLOAD_LDS16(kg1 + kofs, &Klds[nxt][(tid + 256) * 8]);
      GLOAD_LDS16(vg0 + vofs, &Vlds[nxt][tid * 8]);
      GLOAD_LDS16(vg1 + vofs, &Vlds[nxt][(tid + 256) * 8]);
      asm volatile("s_waitcnt vmcnt(4)" ::: "memory");
    } else {
      asm volatile("s_waitcnt vmcnt(0)" ::: "memory");
    }
    __builtin_amdgcn_s_barrier();
    __builtin_amdgcn_sched_barrier(0);

    const int kv0 = it << 6;
#pragma unroll
    for (int s = 0; s < 2; ++s) {
      int tt[2][2];
#pragma unroll
      for (int half = 0; half < 2; ++half) {
        const int kvt = (s << 1) + half;
        const int kr = ((kvt << 4) + lr) << 6;
        const bf16x8 ka0 = *(const bf16x8*)&Klds[cur][kr + ((quad ^ xk) << 3)];
        const bf16x8 ka1 = *(const bf16x8*)&Klds[cur][kr + (((4 + quad) ^ xk) << 3)];
        f32x4 d = {0.f, 0.f, 0.f, 0.f};
        __builtin_amdgcn_s_setprio(1);
        d = MFMA_BF16(ka0, qf0, d);
        d = MFMA_BF16(ka1, qf1, d);
        __builtin_amdgcn_s_setprio(0);
        const f32x4 lg = *(const f32x4*)&Rlds[kv0 + (kvt << 4) + (quad << 2)];
        const float p0 = __builtin_amdgcn_exp2f(fmaf(d[0], kC, lg[0]));
        const float p1 = __builtin_amdgcn_exp2f(fmaf(d[1], kC, lg[1]));
        const float p2 = __builtin_amdgcn_exp2f(fmaf(d[2], kC, lg[2]));
        const float p3 = __builtin_amdgcn_exp2f(fmaf(d[3], kC, lg[3]));
        bf16x2 lo2 = {(__bf16)p0, (__bf16)p1};
        bf16x2 hi2 = {(__bf16)p2, (__bf16)p3};
        tt[half][0] = __builtin_bit_cast(int, lo2);
        tt[half][1] = __builtin_bit_cast(int, hi2);
      }
      const int vA0 = qodd ? tt[1][0] : tt[0][0];
      const int vA1 = qodd ? tt[1][1] : tt[0][1];
      const int vB0 = qodd ? tt[0][0] : tt[1][0];
      const int vB1 = qodd ? tt[0][1] : tt[1][1];
      const int ra0 = __builtin_amdgcn_ds_permute(addrA, vA0);
      const int ra1 = __builtin_amdgcn_ds_permute(addrA, vA1);
      const int rb0 = __builtin_amdgcn_ds_permute(addrB, vB0);
      const int rb1 = __builtin_amdgcn_ds_permute(addrB, vB1);
      int4 ai;
      ai.x = hiq ? rb0 : ra0;
      ai.y = hiq ? rb1 : ra1;
      ai.z = hiq ? ra0 : rb0;
      ai.w = hiq ? ra1 : rb1;
      const bf16x8 pa = __builtin_bit_cast(bf16x8, ai);
      __builtin_amdgcn_s_setprio(1);
      accL = MFMA_BF16(pa, onesf, accL);
#pragma unroll
      for (int dt = 0; dt < 4; ++dt) {
        const bf16x8 vb = *(const bf16x8*)&Vlds[cur][(((dt << 4) + lr) << 6) +
                                                     ((((s << 2) + quad) ^ xk) << 3)];
        accO[dt] = MFMA_BF16(pa, vb, accO[dt]);
      }
      __builtin_amdgcn_s_setprio(0);
    }
    asm volatile("" ::: "memory");
    __builtin_amdgcn_sched_barrier(0);
    __builtin_amdgcn_s_barrier();
  }

  float linv[4];
#pragma unroll
  for (int r = 0; r < 4; ++r) linv[r] = 1.f / accL[r];

#pragma unroll
  for (int dt = 0; dt < 4; ++dt) {
    const int dcol = (h << 6) + (dt << 4) + lr;
#pragma unroll
    for (int r = 0; r < 4; ++r) {
      const int qg = q0 + (wave << 4) + (quad << 2) + r;
      AO[((size_t)(b << 10) + qg) * kDim + dcol] = (__bf16)(accO[dt][r] * linv[r]);
    }
  }
}

extern "C" void kernel_launch(void* const* d_in, const int* in_sizes, int n_in,
                              void* d_out, int out_size, void* d_ws, size_t ws_size,
                              hipStream_t stream) {
  (void)in_sizes; (void)n_in; (void)out_size; (void)ws_size;
  const float* qf  = (const float*)d_in[0];
  const float* kvf = (const float*)d_in[1];
  const float* rel = (const float*)d_in[2];
  const float* Wq  = (const float*)d_in[3];
  const float* bq  = (const float*)d_in[4];
  const float* Wk  = (const float*)d_in[5];
  const float* bk  = (const float*)d_in[6];
  const float* Wv  = (const float*)d_in[7];
  const float* bv  = (const float*)d_in[8];
  const float* Wo  = (const float*)d_in[9];
  const float* bo  = (const float*)d_in[10];

  const size_t big = (size_t)kB * 1024 * kDim;  // 4M elements
  __bf16* p = (__bf16*)d_ws;
  __bf16* cqf  = p; p += big;
  __bf16* ckvf = p; p += big;
  __bf16* cWq  = p; p += kDim * kDim;
  __bf16* cWk  = p; p += kDim * kDim;
  __bf16* cWv  = p; p += kDim * kDim;
  __bf16* cWo  = p; p += kDim * kDim;
  __bf16* q_buf  = p; p += big;
  __bf16* k_buf  = p; p += big;
  __bf16* vT_buf = p; p += big;
  __bf16* ao_buf = p; p += big;
  float* l2rel = (float*)p;  // 4096 floats (16 KB)

  ConvArgs cv;
  const float* srcs[6] = {qf, kvf, Wq, Wk, Wv, Wo};
  __bf16* dsts[6] = {cqf, ckvf, cWq, cWk, cWv, cWo};
  const int n4s[6] = {(int)(big >> 2), (int)(big >> 2),
                      kDim * kDim / 4, kDim * kDim / 4, kDim * kDim / 4, kDim * kDim / 4};
  for (int i = 0; i < 6; ++i) { cv.src[i] = srcs[i]; cv.dst[i] = dsts[i]; cv.n4[i] = n4s[i]; }
  cv.rel = rel;
  cv.l2rel = l2rel;
  cv.reln4 = (kB * kNKV) / 4;
  convert7<<<dim3(256, 7), 256, 0, stream>>>(cv);

  QKVArgs qa;
  qa.A[0] = cqf;  qa.A[1] = ckvf; qa.A[2] = ckvf;
  qa.W[0] = cWq;  qa.W[1] = cWk;  qa.W[2] = cWv;
  qa.bias[0] = bq; qa.bias[1] = bk; qa.bias[2] = bv;
  qa.rel = rel;
  qa.out[0] = q_buf; qa.out[1] = k_buf; qa.out[2] = vT_buf;
  qkv_gemm<<<768, 128, 0, stream>>>(qa);

  attn_fused<<<kB * kHeads * (1024 / 64), 256, 0, stream>>>(q_buf, k_buf, vT_buf, l2rel, ao_buf);

  o_gemm<<<512, 256, 0, stream>>>(ao_buf, cWo, bo, (float*)d_out);
}

// Round 14
// 184.506 us; speedup vs baseline: 1.2267x; 1.0181x over previous
//
#include <hip/hip_runtime.h>
#include <hip/hip_bf16.h>

typedef __bf16 bf16x8 __attribute__((ext_vector_type(8)));
typedef __bf16 bf16x4 __attribute__((ext_vector_type(4)));
typedef __bf16 bf16x2 __attribute__((ext_vector_type(2)));
typedef float  f32x4  __attribute__((ext_vector_type(4)));

#define MFMA_BF16(a, b, c) __builtin_amdgcn_mfma_f32_16x16x32_bf16((a), (b), (c), 0, 0, 0)

#define GLOAD_LDS16(g, l)                                          \
  __builtin_amdgcn_global_load_lds(                                \
      (const __attribute__((address_space(1))) void*)(g),          \
      (__attribute__((address_space(3))) void*)(l), 16, 0, 0)

static constexpr int kDim = 1024;
static constexpr int kHeads = 16;
static constexpr int kB = 4;
static constexpr int kNKV = 1024;

// ---------------------------------------------------------------------------
// fp32 -> bf16 canonicalization + log2(clamped reliability) precompute.
// ---------------------------------------------------------------------------
struct ConvArgs {
  const float* src[6];
  __bf16* dst[6];
  int n4[6];
  const float* rel;
  float* l2rel;
  int reln4;
};
__global__ __launch_bounds__(256) void convert7(ConvArgs a) {
  const int w = blockIdx.y;
  const int stride = gridDim.x * blockDim.x;
  if (w == 6) {
    for (int i = blockIdx.x * blockDim.x + threadIdx.x; i < a.reln4; i += stride) {
      const float4 v = ((const float4*)a.rel)[i];
      float4 o;
      o.x = __builtin_amdgcn_logf(fmaxf(v.x, 1e-6f));
      o.y = __builtin_amdgcn_logf(fmaxf(v.y, 1e-6f));
      o.z = __builtin_amdgcn_logf(fmaxf(v.z, 1e-6f));
      o.w = __builtin_amdgcn_logf(fmaxf(v.w, 1e-6f));
      ((float4*)a.l2rel)[i] = o;
    }
    return;
  }
  const float4* __restrict__ s = (const float4*)a.src[w];
  __bf16* __restrict__ d = a.dst[w];
  const int n4 = a.n4[w];
  for (int i = blockIdx.x * blockDim.x + threadIdx.x; i < n4; i += stride) {
    const float4 v = s[i];
    bf16x4 o = {(__bf16)v.x, (__bf16)v.y, (__bf16)v.z, (__bf16)v.w};
    *(bf16x4*)(d + (size_t)i * 4) = o;
  }
}

// ---------------------------------------------------------------------------
// QKV NT-GEMM r16 (round-11/13 winner, unchanged): 128x128 tile, 768 blocks,
// 34816 B LDS (Ct aliased), 128-thread 2-wave blocks, wave owns 64x128.
// ---------------------------------------------------------------------------
struct QKVArgs {
  const __bf16* A[3];
  const __bf16* W[3];
  const float* bias[3];
  const float* rel;
  __bf16* out[3];
};

__global__ __launch_bounds__(128, 2) void qkv_gemm(QKVArgs args) {
  constexpr int K = kDim;
  constexpr int CT_STRIDE = 136;
  __shared__ __bf16 smem[128 * CT_STRIDE];
  __bf16* const As = smem;
  __bf16* const Bs = smem + 128 * 64;
  __bf16* const Ct = smem;
  const int bid = blockIdx.x;
  const int x = bid & 7, t = bid >> 3;
  const int z = t >> 5, j = t & 31;                 // z slowest: Q, K, V phases
  const int m_blk = (x << 2) + (j >> 3), n_blk = j & 7;
  const int m0 = m_blk << 7, n0 = n_blk << 7;
  const int bb = m_blk >> 3;
  const __bf16* __restrict__ A = args.A[z];
  const __bf16* __restrict__ W = args.W[z];
  const float* __restrict__ bias = args.bias[z];
  const float* __restrict__ rel = args.rel;
  __bf16* __restrict__ out = args.out[z];

  const int tid = threadIdx.x;
  const int wave = tid >> 6, lane = tid & 63;
  const int lr = lane & 15, quad = lane >> 4;
  const int wm = wave << 6;                         // wave owns 64 m-rows

  f32x4 acc[4][8] = {};

  for (int k0 = 0; k0 < K; k0 += 64) {
    __syncthreads();
#pragma unroll
    for (int i = 0; i < 8; ++i) {               // A: 1024 16B chunks
      const int sc = tid + (i << 7);
      const int row = sc >> 3, cp = sc & 7;
      const int gcol = (cp ^ (row & 7)) << 3;
      GLOAD_LDS16(A + (size_t)(m0 + row) * K + k0 + gcol, As + sc * 8);
    }
#pragma unroll
    for (int i = 0; i < 8; ++i) {               // B: 1024 16B chunks
      const int sc = tid + (i << 7);
      const int row = sc >> 3, cp = sc & 7;
      const int gcol = (cp ^ (row & 7)) << 3;
      GLOAD_LDS16(W + (size_t)(n0 + row) * K + k0 + gcol, Bs + sc * 8);
    }
    __syncthreads();
#pragma unroll
    for (int kk = 0; kk < 2; ++kk) {
      bf16x8 afr[4], bfr[8];
#pragma unroll
      for (int mi = 0; mi < 4; ++mi) {
        const int row = wm + mi * 16 + lr;
        afr[mi] = *(const bf16x8*)&As[(row << 6) +
                                      ((((kk << 2) + quad) ^ (row & 7)) << 3)];
      }
#pragma unroll
      for (int ni = 0; ni < 8; ++ni) {
        const int row = ni * 16 + lr;
        bfr[ni] = *(const bf16x8*)&Bs[(row << 6) +
                                      ((((kk << 2) + quad) ^ (row & 7)) << 3)];
      }
#pragma unroll
      for (int mi = 0; mi < 4; ++mi)
#pragma unroll
        for (int ni = 0; ni < 8; ++ni)
          acc[mi][ni] = MFMA_BF16(afr[mi], bfr[ni], acc[mi][ni]);
    }
  }

  // All waves done reading As/Bs before Ct (same storage) is written.
  __syncthreads();

  // Epilogue: D layout row=(lane>>4)*4+r, col=lane&15 (verified).
#pragma unroll
  for (int mi = 0; mi < 4; ++mi)
#pragma unroll
    for (int ni = 0; ni < 8; ++ni) {
      const int col_l = ni * 16 + lr;
      const float bc = bias[n0 + col_l];
      const f32x4 v = acc[mi][ni];
      const int row0 = wm + mi * 16 + (quad << 2);
      if (z == 2) {
        const f32x4 r4 = *(const f32x4*)(rel + (bb << 10) + ((m0 + row0) & 1023));
        bf16x4 pk;
#pragma unroll
        for (int r = 0; r < 4; ++r) pk[r] = (__bf16)((v[r] + bc) * r4[r]);
        *(bf16x4*)&Ct[col_l * CT_STRIDE + row0] = pk;
      } else if (z == 1) {
        const f32x4 r4 = *(const f32x4*)(rel + (bb << 10) + ((m0 + row0) & 1023));
#pragma unroll
        for (int r = 0; r < 4; ++r)
          Ct[(row0 + r) * CT_STRIDE + col_l] = (__bf16)((v[r] + bc) * r4[r]);
      } else {
#pragma unroll
        for (int r = 0; r < 4; ++r)
          Ct[(row0 + r) * CT_STRIDE + col_l] = (__bf16)(v[r] + bc);
      }
    }
  __syncthreads();

  const int hh0 = n0 >> 6;
  if (z == 2) {
#pragma unroll
    for (int jj = 0; jj < 16; ++jj) {
      const int idx = (jj << 7) + tid;
      const int c = idx >> 4, r8 = (idx & 15) << 3;
      const bf16x8 vv = *(const bf16x8*)&Ct[c * CT_STRIDE + r8];
      const int col = n0 + c;
      const int hh = col >> 6, dd = col & 63;
      *(bf16x8*)(out + ((size_t)(bb * kHeads + hh) * 64 + dd) * 1024 +
                 (m0 & 1023) + r8) = vv;
    }
  } else {
#pragma unroll
    for (int jj = 0; jj < 16; ++jj) {
      const int idx = (jj << 7) + tid;
      const int r = idx >> 4, c8 = (idx & 15) << 3;
      const bf16x8 vv = *(const bf16x8*)&Ct[r * CT_STRIDE + c8];
      const int hh = hh0 + (c8 >> 6), dd = c8 & 63;
      *(bf16x8*)(out + ((size_t)(bb * kHeads + hh) << 16) +
                 (size_t)((m0 & 1023) + r) * 64 + dd) = vv;
    }
  }
}

// ---------------------------------------------------------------------------
// O-projection r13 (round-8 winner, unchanged: 128x64 tile, 512 blocks =
// 2 blocks/CU, dbuf + counted vmcnt(6)).
// ---------------------------------------------------------------------------
__global__ __launch_bounds__(256) void o_gemm(const __bf16* __restrict__ A,
                                              const __bf16* __restrict__ W,
                                              const float* __restrict__ bias,
                                              float* __restrict__ out) {
  constexpr int K = kDim;
  __shared__ __bf16 As[2][128 * 64];
  __shared__ __bf16 Bs[2][64 * 64];
  const int bid = blockIdx.x;
  const int x = bid & 7, t = bid >> 3;
  const int m_blk = (x << 2) + (t & 3), n_blk = t >> 2;
  const int m0 = m_blk << 7, n0 = n_blk << 6;
  const int tid = threadIdx.x;
  const int wave = tid >> 6, lane = tid & 63;
  const int lr = lane & 15, quad = lane >> 4;
  const int wm = wave << 5;

  const __bf16* aP[4];
  int soA[4];
#pragma unroll
  for (int i = 0; i < 4; ++i) {
    const int sc = tid + (i << 8);
    const int row = sc >> 3, cp = sc & 7;
    const int gcol = (cp ^ (row & 7)) << 3;
    aP[i] = A + (size_t)(m0 + row) * K + gcol;
    soA[i] = sc * 8;
  }
  const __bf16* bP[2];
  int soB[2];
#pragma unroll
  for (int i = 0; i < 2; ++i) {
    const int sc = tid + (i << 8);
    const int row = sc >> 3, cp = sc & 7;
    const int gcol = (cp ^ (row & 7)) << 3;
    bP[i] = W + (size_t)(n0 + row) * K + gcol;
    soB[i] = sc * 8;
  }

#pragma unroll
  for (int i = 0; i < 4; ++i) GLOAD_LDS16(aP[i], &As[0][soA[i]]);
#pragma unroll
  for (int i = 0; i < 2; ++i) GLOAD_LDS16(bP[i], &Bs[0][soB[i]]);

  f32x4 acc[2][4] = {};
  for (int tile = 0; tile < 16; ++tile) {
    const int cur = tile & 1;
    if (tile < 15) {
      const int k0 = (tile + 1) << 6;
      const int nxt = cur ^ 1;
#pragma unroll
      for (int i = 0; i < 4; ++i) GLOAD_LDS16(aP[i] + k0, &As[nxt][soA[i]]);
#pragma unroll
      for (int i = 0; i < 2; ++i) GLOAD_LDS16(bP[i] + k0, &Bs[nxt][soB[i]]);
      asm volatile("s_waitcnt vmcnt(6)" ::: "memory");
    } else {
      asm volatile("s_waitcnt vmcnt(0)" ::: "memory");
    }
    __builtin_amdgcn_s_barrier();
    __builtin_amdgcn_sched_barrier(0);

    const __bf16* Asc = As[cur];
    const __bf16* Bsc = Bs[cur];
#pragma unroll
    for (int kk = 0; kk < 2; ++kk) {
      bf16x8 afr[2], bfr[4];
#pragma unroll
      for (int mi = 0; mi < 2; ++mi) {
        const int row = wm + mi * 16 + lr;
        afr[mi] = *(const bf16x8*)&Asc[(row << 6) +
                                       ((((kk << 2) + quad) ^ (row & 7)) << 3)];
      }
#pragma unroll
      for (int ni = 0; ni < 4; ++ni) {
        const int row = ni * 16 + lr;
        bfr[ni] = *(const bf16x8*)&Bsc[(row << 6) +
                                       ((((kk << 2) + quad) ^ (row & 7)) << 3)];
      }
#pragma unroll
      for (int mi = 0; mi < 2; ++mi)
#pragma unroll
        for (int ni = 0; ni < 4; ++ni)
          acc[mi][ni] = MFMA_BF16(afr[mi], bfr[ni], acc[mi][ni]);
    }
    asm volatile("" ::: "memory");
    __builtin_amdgcn_sched_barrier(0);
    __builtin_amdgcn_s_barrier();
  }

#pragma unroll
  for (int mi = 0; mi < 2; ++mi)
#pragma unroll
    for (int ni = 0; ni < 4; ++ni) {
      const int col = n0 + ni * 16 + lr;
      const float bc = bias[col];
      const f32x4 v = acc[mi][ni];
#pragma unroll
      for (int r = 0; r < 4; ++r) {
        const int row = m0 + wm + mi * 16 + (quad << 2) + r;
        out[(size_t)row * kDim + col] = v[r] + bc;
      }
    }
}

// ---------------------------------------------------------------------------
// Fused attention r18: QBLK=128, 8 waves / 512 threads, grid 512 = 2
// blocks/CU. Waves/CU unchanged (16 — round-4 lesson respected); inner loop
// byte-identical to r14 (each wave owns 16 q-rows). Per 256 q-rows a CU now
// pays HALF the staging writes, gload_lds issues, HBM K/V re-reads and
// barrier-drain events (2 blocks instead of 4 cover the same q-rows).
// Staging: 1 chunk/thread (512 threads cover 64x64 tile), vmcnt(2).
// ---------------------------------------------------------------------------
__global__ __launch_bounds__(512, 4) void attn_fused(const __bf16* __restrict__ Qb,
                                                     const __bf16* __restrict__ Kb,
                                                     const __bf16* __restrict__ Vb,
                                                     const float* __restrict__ l2rel,
                                                     __bf16* __restrict__ AO) {
  __shared__ __bf16 Klds[2][64 * 64];
  __shared__ __bf16 Vlds[2][64 * 64];
  __shared__ float Rlds[1024];
  const int tid = threadIdx.x;
  const int wave = tid >> 6, lane = tid & 63;
  const int lr = lane & 15, quad = lane >> 4;
  const int x = blockIdx.x & 7, g = blockIdx.x >> 3;   // g 0..63
  const int hg = x + ((g & 7) << 3);                   // 0..63
  const int b = hg >> 4, h = hg & 15, q0 = (g >> 3) << 7;  // q-block of 128
  const __bf16* Qh = Qb + ((size_t)hg << 16);
  const __bf16* Kh = Kb + ((size_t)hg << 16);
  const __bf16* Vh = Vb + ((size_t)hg << 16);
  const float* rb = l2rel + (b << 10);

  if (tid < 256) ((f32x4*)Rlds)[tid] = ((const f32x4*)rb)[tid];

  const __bf16* qrow = Qh + (q0 + (wave << 4) + lr) * 64 + (quad << 3);
  const bf16x8 qf0 = *(const bf16x8*)qrow;
  const bf16x8 qf1 = *(const bf16x8*)(qrow + 32);

  // Staging: 1 chunk of 16B per matrix per thread (512 chunks = 64x64 tile).
  const int r0 = tid >> 3, c0 = tid & 7;
  const int gc0 = (c0 ^ (r0 & 7)) << 3;
  const __bf16* kg0 = Kh + (size_t)r0 * 64 + gc0;
  const __bf16* vg0 = Vh + (size_t)r0 * kNKV + gc0;

  asm volatile("s_waitcnt lgkmcnt(0)" ::: "memory");

  GLOAD_LDS16(kg0, &Klds[0][tid * 8]);
  GLOAD_LDS16(vg0, &Vlds[0][tid * 8]);

  f32x4 accO[4] = {{0.f, 0.f, 0.f, 0.f}, {0.f, 0.f, 0.f, 0.f},
                   {0.f, 0.f, 0.f, 0.f}, {0.f, 0.f, 0.f, 0.f}};
  f32x4 accL = {0.f, 0.f, 0.f, 0.f};
  const bf16x8 onesf = {(__bf16)1.f, (__bf16)1.f, (__bf16)1.f, (__bf16)1.f,
                        (__bf16)1.f, (__bf16)1.f, (__bf16)1.f, (__bf16)1.f};
  const int xk = lr & 7;
  constexpr float kC = 0.125f * 1.44269504088896341f;  // scale * log2(e)

  const int addrA = ((((quad & 1) << 1) + (quad >> 1)) << 6) + (lr << 2);
  const int addrB = addrA ^ 128;
  const bool qodd = (quad & 1) != 0;
  const bool hiq = quad >= 2;

  for (int it = 0; it < 16; ++it) {
    const int cur = it & 1;
    if (it < 15) {
      const int nxt = cur ^ 1;
      const size_t kofs = (size_t)(it + 1) << 12;  // 64 rows x 64 cols
      const size_t vofs = (size_t)(it + 1) << 6;   // +64 kv cols
      GLOAD_LDS16(kg0 + kofs, &Klds[nxt][tid * 8]);
      GLOAD_LDS16(vg0 + vofs, &Vlds[nxt][tid * 8]);
      asm volatile("s_waitcnt vmcnt(2)" ::: "memory");  // cur's 2 complete
    } else {
      asm volatile("s_waitcnt vmcnt(0)" ::: "memory");
    }
    __builtin_amdgcn_s_barrier();
    __builtin_amdgcn_sched_barrier(0);

    const int kv0 = it << 6;
#pragma unroll
    for (int s = 0; s < 2; ++s) {
      int tt[2][2];
#pragma unroll
      for (int half = 0; half < 2; ++half) {
        const int kvt = (s << 1) + half;
        const int kr = ((kvt << 4) + lr) << 6;
        const bf16x8 ka0 = *(const bf16x8*)&Klds[cur][kr + ((quad ^ xk) << 3)];
        const bf16x8 ka1 = *(const bf16x8*)&Klds[cur][kr + (((4 + quad) ^ xk) << 3)];
        f32x4 d = {0.f, 0.f, 0.f, 0.f};
        __builtin_amdgcn_s_setprio(1);
        d = MFMA_BF16(ka0, qf0, d);
        d = MFMA_BF16(ka1, qf1, d);
        __builtin_amdgcn_s_setprio(0);
        const f32x4 lg = *(const f32x4*)&Rlds[kv0 + (kvt << 4) + (quad << 2)];
        const float p0 = __builtin_amdgcn_exp2f(fmaf(d[0], kC, lg[0]));
        const float p1 = __builtin_amdgcn_exp2f(fmaf(d[1], kC, lg[1]));
        const float p2 = __builtin_amdgcn_exp2f(fmaf(d[2], kC, lg[2]));
        const float p3 = __builtin_amdgcn_exp2f(fmaf(d[3], kC, lg[3]));
        bf16x2 lo2 = {(__bf16)p0, (__bf16)p1};
        bf16x2 hi2 = {(__bf16)p2, (__bf16)p3};
        tt[half][0] = __builtin_bit_cast(int, lo2);
        tt[half][1] = __builtin_bit_cast(int, hi2);
      }
      const int vA0 = qodd ? tt[1][0] : tt[0][0];
      const int vA1 = qodd ? tt[1][1] : tt[0][1];
      const int vB0 = qodd ? tt[0][0] : tt[1][0];
      const int vB1 = qodd ? tt[0][1] : tt[1][1];
      const int ra0 = __builtin_amdgcn_ds_permute(addrA, vA0);
      const int ra1 = __builtin_amdgcn_ds_permute(addrA, vA1);
      const int rb0 = __builtin_amdgcn_ds_permute(addrB, vB0);
      const int rb1 = __builtin_amdgcn_ds_permute(addrB, vB1);
      int4 ai;
      ai.x = hiq ? rb0 : ra0;
      ai.y = hiq ? rb1 : ra1;
      ai.z = hiq ? ra0 : rb0;
      ai.w = hiq ? ra1 : rb1;
      const bf16x8 pa = __builtin_bit_cast(bf16x8, ai);
      __builtin_amdgcn_s_setprio(1);
      accL = MFMA_BF16(pa, onesf, accL);
#pragma unroll
      for (int dt = 0; dt < 4; ++dt) {
        const bf16x8 vb = *(const bf16x8*)&Vlds[cur][(((dt << 4) + lr) << 6) +
                                                     ((((s << 2) + quad) ^ xk) << 3)];
        accO[dt] = MFMA_BF16(pa, vb, accO[dt]);
      }
      __builtin_amdgcn_s_setprio(0);
    }
    asm volatile("" ::: "memory");
    __builtin_amdgcn_sched_barrier(0);
    __builtin_amdgcn_s_barrier();
  }

  float linv[4];
#pragma unroll
  for (int r = 0; r < 4; ++r) linv[r] = 1.f / accL[r];

#pragma unroll
  for (int dt = 0; dt < 4; ++dt) {
    const int dcol = (h << 6) + (dt << 4) + lr;
#pragma unroll
    for (int r = 0; r < 4; ++r) {
      const int qg = q0 + (wave << 4) + (quad << 2) + r;
      AO[((size_t)(b << 10) + qg) * kDim + dcol] = (__bf16)(accO[dt][r] * linv[r]);
    }
  }
}

extern "C" void kernel_launch(void* const* d_in, const int* in_sizes, int n_in,
                              void* d_out, int out_size, void* d_ws, size_t ws_size,
                              hipStream_t stream) {
  (void)in_sizes; (void)n_in; (void)out_size; (void)ws_size;
  const float* qf  = (const float*)d_in[0];
  const float* kvf = (const float*)d_in[1];
  const float* rel = (const float*)d_in[2];
  const float* Wq  = (const float*)d_in[3];
  const float* bq  = (const float*)d_in[4];
  const float* Wk  = (const float*)d_in[5];
  const float* bk  = (const float*)d_in[6];
  const float* Wv  = (const float*)d_in[7];
  const float* bv  = (const float*)d_in[8];
  const float* Wo  = (const float*)d_in[9];
  const float* bo  = (const float*)d_in[10];

  const size_t big = (size_t)kB * 1024 * kDim;  // 4M elements
  __bf16* p = (__bf16*)d_ws;
  __bf16* cqf  = p; p += big;
  __bf16* ckvf = p; p += big;
  __bf16* cWq  = p; p += kDim * kDim;
  __bf16* cWk  = p; p += kDim * kDim;
  __bf16* cWv  = p; p += kDim * kDim;
  __bf16* cWo  = p; p += kDim * kDim;
  __bf16* q_buf  = p; p += big;
  __bf16* k_buf  = p; p += big;
  __bf16* vT_buf = p; p += big;
  __bf16* ao_buf = p; p += big;
  float* l2rel = (float*)p;  // 4096 floats (16 KB)

  ConvArgs cv;
  const float* srcs[6] = {qf, kvf, Wq, Wk, Wv, Wo};
  __bf16* dsts[6] = {cqf, ckvf, cWq, cWk, cWv, cWo};
  const int n4s[6] = {(int)(big >> 2), (int)(big >> 2),
                      kDim * kDim / 4, kDim * kDim / 4, kDim * kDim / 4, kDim * kDim / 4};
  for (int i = 0; i < 6; ++i) { cv.src[i] = srcs[i]; cv.dst[i] = dsts[i]; cv.n4[i] = n4s[i]; }
  cv.rel = rel;
  cv.l2rel = l2rel;
  cv.reln4 = (kB * kNKV) / 4;
  convert7<<<dim3(256, 7), 256, 0, stream>>>(cv);

  QKVArgs qa;
  qa.A[0] = cqf;  qa.A[1] = ckvf; qa.A[2] = ckvf;
  qa.W[0] = cWq;  qa.W[1] = cWk;  qa.W[2] = cWv;
  qa.bias[0] = bq; qa.bias[1] = bk; qa.bias[2] = bv;
  qa.rel = rel;
  qa.out[0] = q_buf; qa.out[1] = k_buf; qa.out[2] = vT_buf;
  qkv_gemm<<<768, 128, 0, stream>>>(qa);

  attn_fused<<<512, 512, 0, stream>>>(q_buf, k_buf, vT_buf, l2rel, ao_buf);

  o_gemm<<<512, 256, 0, stream>>>(ao_buf, cWo, bo, (float*)d_out);
}